// Round 8
// baseline (233.867 us; speedup 1.0000x reference)
//
#include <hip/hip_runtime.h>
#include <hip/hip_bf16.h>
#include <math.h>

#define N_TOK 4096
#define D_DIM 512
#define E_NUM 8
#define H_DIM 256

typedef __attribute__((ext_vector_type(8))) short short8v;   // 8 bf16 = 4 VGPR
typedef __attribute__((ext_vector_type(4))) float floatx4;   // MFMA acc

__device__ inline floatx4 mfma_bf16(short8v a, short8v b, floatx4 c) {
    return __builtin_amdgcn_mfma_f32_16x16x32_bf16(a, b, c, 0, 0, 0);
}

__device__ inline unsigned short f2bf(float f) {           // RNE fp32->bf16
    union { float f; unsigned u; } v; v.f = f;
    unsigned r = v.u + 0x7FFFu + ((v.u >> 16) & 1u);
    return (unsigned short)(r >> 16);
}
__device__ inline unsigned pack2(float a, float b) {
    return (unsigned)f2bf(a) | ((unsigned)f2bf(b) << 16);
}
__device__ inline void calc_offs(const int* __restrict__ counts, int* offs) {
    int a = 0;
    #pragma unroll
    for (int e = 0; e < E_NUM; e++) { offs[e] = a; a += counts[e]; }
    offs[E_NUM] = a;
}

// ---------------------------------------------------------------------------
__global__ void init_kernel(int* counts, int* nextp) {
    int t = threadIdx.x;
    if (t < 16) { counts[t] = 0; nextp[t] = 0; }
}

// ---------------------------------------------------------------------------
// router v2: one wave per 4 tokens, R held in registers (64 f32/lane slice),
// coalesced float4 x loads, butterfly shuffle reduce, exact fp32 softmax/top-2
// (strict > keeps lowest index). 256 blocks x 4 waves = 1024 waves.
// ---------------------------------------------------------------------------
__global__ __launch_bounds__(256)
void router_kernel(const float* __restrict__ x, const float* __restrict__ router,
                   int* __restrict__ topk_idx, float* __restrict__ topk_sc,
                   int* __restrict__ counts) {
    __shared__ int csh[E_NUM];
    int t = threadIdx.x;
    if (t < E_NUM) csh[t] = 0;
    __syncthreads();

    int wave = t >> 6, lane = t & 63;

    // R fragment: R[q][e] = router[(lane*8+q)*E + e], per-lane d-slice in regs
    float R[8][8];
    #pragma unroll
    for (int q = 0; q < 8; q++) {
        #pragma unroll
        for (int h = 0; h < 2; h++) {
            float4 v = *reinterpret_cast<const float4*>(
                router + (size_t)(lane * 8 + q) * E_NUM + h * 4);
            R[q][h * 4 + 0] = v.x; R[q][h * 4 + 1] = v.y;
            R[q][h * 4 + 2] = v.z; R[q][h * 4 + 3] = v.w;
        }
    }

    int cnt[E_NUM];
    #pragma unroll
    for (int e = 0; e < E_NUM; e++) cnt[e] = 0;

    #pragma unroll
    for (int it = 0; it < 4; it++) {
        int n = (blockIdx.x * 4 + wave) * 4 + it;
        const float* xr = x + (size_t)n * D_DIM + lane * 8;
        float4 xa = *reinterpret_cast<const float4*>(xr);
        float4 xb = *reinterpret_cast<const float4*>(xr + 4);
        float xs[8] = {xa.x, xa.y, xa.z, xa.w, xb.x, xb.y, xb.z, xb.w};

        float acc[E_NUM];
        #pragma unroll
        for (int e = 0; e < E_NUM; e++) acc[e] = 0.f;
        #pragma unroll
        for (int q = 0; q < 8; q++)
            #pragma unroll
            for (int e = 0; e < E_NUM; e++)
                acc[e] = fmaf(xs[q], R[q][e], acc[e]);

        // butterfly reduce across 64 lanes (all lanes end with full sums)
        #pragma unroll
        for (int s = 1; s < 64; s <<= 1) {
            #pragma unroll
            for (int e = 0; e < E_NUM; e++)
                acc[e] += __shfl_xor(acc[e], s);
        }

        float mx = acc[0];
        #pragma unroll
        for (int e = 1; e < E_NUM; e++) mx = fmaxf(mx, acc[e]);
        float p[E_NUM], s = 0.f;
        #pragma unroll
        for (int e = 0; e < E_NUM; e++) { p[e] = expf(acc[e] - mx); s += p[e]; }
        float inv = 1.f / s;

        int i0 = 0; float p0 = p[0];
        #pragma unroll
        for (int e = 1; e < E_NUM; e++)
            if (p[e] > p0) { p0 = p[e]; i0 = e; }
        int i1 = -1; float p1 = -1.f;
        #pragma unroll
        for (int e = 0; e < E_NUM; e++)
            if (e != i0 && p[e] > p1) { p1 = p[e]; i1 = e; }

        if (lane == 0) {
            topk_idx[n * 2 + 0] = i0;
            topk_idx[n * 2 + 1] = i1;
            topk_sc[n * 2 + 0]  = p0 * inv;
            topk_sc[n * 2 + 1]  = p1 * inv;
            #pragma unroll
            for (int e = 0; e < E_NUM; e++)
                cnt[e] += (i0 == e) + (i1 == e);
        }
    }
    if (lane == 0) {
        #pragma unroll
        for (int e = 0; e < E_NUM; e++)
            if (cnt[e]) atomicAdd(&csh[e], cnt[e]);
    }
    __syncthreads();
    if (t < E_NUM && csh[t]) atomicAdd(&counts[t], csh[t]);
}

// ---------------------------------------------------------------------------
// place: compact per-expert token lists (order within an expert is irrelevant)
// ---------------------------------------------------------------------------
__global__ __launch_bounds__(256)
void place_kernel(const int* __restrict__ topk_idx, const float* __restrict__ topk_sc,
                  const int* __restrict__ counts, int* __restrict__ nextp,
                  int* __restrict__ list_tok, float* __restrict__ list_sc) {
    int offs[E_NUM + 1];
    calc_offs(counts, offs);
    int n = blockIdx.x * 256 + threadIdx.x;
    int lane = threadIdx.x & 63;
    for (int k = 0; k < 2; k++) {
        int e = topk_idx[n * 2 + k];
        float sc = topk_sc[n * 2 + k];
        #pragma unroll
        for (int ee = 0; ee < E_NUM; ee++) {
            unsigned long long m = __ballot(e == ee);
            if (m == 0ull) continue;
            int leader = __ffsll((long long)m) - 1;
            int base = 0;
            if (lane == leader) base = atomicAdd(&nextp[ee], (int)__popcll(m));
            base = __shfl(base, leader);
            if (e == ee) {
                int pos = base + (int)__popcll(m & ((1ull << lane) - 1ull));
                int slot = offs[ee] + pos;
                list_tok[slot] = n;
                list_sc[slot]  = sc;
            }
        }
    }
}

// ---------------------------------------------------------------------------
// prep: transpose + fp32->bf16 all weights into [n][k] (K-contiguous) layout.
// GU family: [512][256] -> [256][512], mats: 0-7 Wg, 8-15 Wu, 16 shg, 17 shu.
// DN family: [256][512] -> [512][256], mats: 0-7 Wd, 8 shd.
// ---------------------------------------------------------------------------
__global__ __launch_bounds__(256)
void prep_kernel(const float* __restrict__ Wg, const float* __restrict__ Wu,
                 const float* __restrict__ shg, const float* __restrict__ shu,
                 const float* __restrict__ Wd, const float* __restrict__ shd,
                 unsigned short* __restrict__ Wg_t, unsigned short* __restrict__ Wu_t,
                 unsigned short* __restrict__ Wd_t) {
    __shared__ float T[32][33];
    int b = blockIdx.x, t = threadIdx.x;
    const float* S; unsigned short* Dt; int K, N, k0, n0;
    if (b < 2304) {
        int mat = b >> 7, tid = b & 127;
        K = 512; N = 256;
        k0 = (tid >> 3) * 32; n0 = (tid & 7) * 32;
        if (mat < 8)       { S = Wg + (size_t)mat * 131072;       Dt = Wg_t + (size_t)mat * 131072; }
        else if (mat < 16) { S = Wu + (size_t)(mat - 8) * 131072; Dt = Wu_t + (size_t)(mat - 8) * 131072; }
        else if (mat == 16){ S = shg;                              Dt = Wg_t + (size_t)8 * 131072; }
        else               { S = shu;                              Dt = Wu_t + (size_t)8 * 131072; }
    } else {
        int id = b - 2304; int mat = id >> 7, tid = id & 127;
        K = 256; N = 512;
        k0 = (tid >> 4) * 32; n0 = (tid & 15) * 32;
        if (mat < 8) { S = Wd + (size_t)mat * 131072; Dt = Wd_t + (size_t)mat * 131072; }
        else         { S = shd;                        Dt = Wd_t + (size_t)8 * 131072; }
    }
    int r = t >> 3, c0 = (t & 7) * 4;
    float4 v = *reinterpret_cast<const float4*>(S + (size_t)(k0 + r) * N + n0 + c0);
    T[r][c0 + 0] = v.x; T[r][c0 + 1] = v.y; T[r][c0 + 2] = v.z; T[r][c0 + 3] = v.w;
    __syncthreads();
    uint2 o;
    o.x = pack2(T[c0 + 0][r], T[c0 + 1][r]);
    o.y = pack2(T[c0 + 2][r], T[c0 + 3][r]);
    *reinterpret_cast<uint2*>(Dt + (size_t)(n0 + r) * K + k0 + c0) = o;
}

// ---------------------------------------------------------------------------
// gemm1 (MFMA bf16): H1 = silu(X@Wg)*(X@Wu) [* score], per segment.
// z: 0..7 routed experts (gathered rows), 8 shared (identity rows).
// Block: 256 thr = 4 waves (2x2), tile 64(M) x 128(N), BK=64.
// LDS tiles XOR-swizzled: byte ^= (row&7)<<4 -> conflict-free ds_read_b128.
// T14 prefetch: loads for k+1 issued before MFMA(k) -> latency hidden.
// ---------------------------------------------------------------------------
__global__ __launch_bounds__(256)
void gemm1_kernel(const float* __restrict__ x,
                  const unsigned short* __restrict__ Wg_t, const unsigned short* __restrict__ Wu_t,
                  const int* __restrict__ counts, const int* __restrict__ list_tok,
                  const float* __restrict__ list_sc,
                  unsigned short* __restrict__ H1s, unsigned short* __restrict__ H1r) {
    int ez = blockIdx.z;
    int offs[E_NUM + 1];
    calc_offs(counts, offs);
    int beg = 0, M;
    if (ez == E_NUM) { M = N_TOK; }
    else { beg = offs[ez]; M = counts[ez]; }
    int m0 = blockIdx.x * 64;
    if (m0 >= M) return;
    int h0 = blockIdx.y * 128;

    __shared__ unsigned short As[64 * 64];
    __shared__ unsigned short Bgs[128 * 64];
    __shared__ unsigned short Bus[128 * 64];
    char* asB = (char*)As;
    char* bgB = (char*)Bgs;
    char* buB = (char*)Bus;

    int t = threadIdx.x;

    // A staging: row=t>>2, two 16B slots (t&3)*2.., fp32 load + bf16 pack
    int arow = t >> 2;
    int as0  = (t & 3) * 2;
    int mrow = m0 + arow;
    int src_row;
    if (ez == E_NUM) src_row = mrow;
    else { int idx = mrow < M ? mrow : M - 1; src_row = list_tok[beg + idx]; }
    const float* ap = x + (size_t)src_row * D_DIM + as0 * 8;
    unsigned aw0 = ((unsigned)(arow * 128 + as0 * 16))       ^ ((arow & 7) << 4);
    unsigned aw1 = ((unsigned)(arow * 128 + (as0 + 1) * 16)) ^ ((arow & 7) << 4);

    // B staging: row=t>>1, four 16B slots (t&1)*4.., bf16 direct
    int brow = t >> 1;
    int bs0  = (t & 1) * 4;
    const unsigned short* gp = Wg_t + (size_t)ez * 131072 + (size_t)(h0 + brow) * D_DIM;
    const unsigned short* up = Wu_t + (size_t)ez * 131072 + (size_t)(h0 + brow) * D_DIM;
    unsigned bw[4];
    #pragma unroll
    for (int s = 0; s < 4; s++)
        bw[s] = ((unsigned)(brow * 128 + (bs0 + s) * 16)) ^ ((brow & 7) << 4);

    // compute-side fragment offsets (loop-invariant)
    int wid = t >> 6, lane = t & 63;
    int wr = wid >> 1, wc = wid & 1;
    int lrow = lane & 15, lk = lane >> 4;
    unsigned aoff[2][2], boff[4][2];
    #pragma unroll
    for (int mf = 0; mf < 2; mf++) {
        int r = wr * 32 + mf * 16 + lrow;
        #pragma unroll
        for (int kf = 0; kf < 2; kf++)
            aoff[mf][kf] = ((unsigned)(r * 128 + lk * 16 + kf * 64)) ^ ((r & 7) << 4);
    }
    #pragma unroll
    for (int nf = 0; nf < 4; nf++) {
        int r = wc * 64 + nf * 16 + lrow;
        #pragma unroll
        for (int kf = 0; kf < 2; kf++)
            boff[nf][kf] = ((unsigned)(r * 128 + lk * 16 + kf * 64)) ^ ((r & 7) << 4);
    }

    floatx4 zf = {0.f, 0.f, 0.f, 0.f};
    floatx4 accg[2][4], accu[2][4];
    #pragma unroll
    for (int i = 0; i < 2; i++)
        #pragma unroll
        for (int j = 0; j < 4; j++) { accg[i][j] = zf; accu[i][j] = zf; }

    // prologue: load k-tile 0 into registers
    float4 af[4];
    uint4 gv[4], uv[4];
    #pragma unroll
    for (int q = 0; q < 4; q++)
        af[q] = *reinterpret_cast<const float4*>(ap + q * 4);
    #pragma unroll
    for (int s = 0; s < 4; s++) {
        gv[s] = *reinterpret_cast<const uint4*>(gp + (bs0 + s) * 8);
        uv[s] = *reinterpret_cast<const uint4*>(up + (bs0 + s) * 8);
    }

    #pragma unroll
    for (int k0 = 0; k0 < D_DIM; k0 += 64) {
        __syncthreads();   // prev iter's LDS reads done
        uint4 u0, u1;
        u0.x = pack2(af[0].x, af[0].y); u0.y = pack2(af[0].z, af[0].w);
        u0.z = pack2(af[1].x, af[1].y); u0.w = pack2(af[1].z, af[1].w);
        u1.x = pack2(af[2].x, af[2].y); u1.y = pack2(af[2].z, af[2].w);
        u1.z = pack2(af[3].x, af[3].y); u1.w = pack2(af[3].z, af[3].w);
        *reinterpret_cast<uint4*>(asB + aw0) = u0;
        *reinterpret_cast<uint4*>(asB + aw1) = u1;
        #pragma unroll
        for (int s = 0; s < 4; s++) {
            *reinterpret_cast<uint4*>(bgB + bw[s]) = gv[s];
            *reinterpret_cast<uint4*>(buB + bw[s]) = uv[s];
        }
        __syncthreads();
        // issue next k-tile's loads now -> in flight during the MFMA cluster
        if (k0 + 64 < D_DIM) {
            #pragma unroll
            for (int q = 0; q < 4; q++)
                af[q] = *reinterpret_cast<const float4*>(ap + k0 + 64 + q * 4);
            #pragma unroll
            for (int s = 0; s < 4; s++) {
                gv[s] = *reinterpret_cast<const uint4*>(gp + k0 + 64 + (bs0 + s) * 8);
                uv[s] = *reinterpret_cast<const uint4*>(up + k0 + 64 + (bs0 + s) * 8);
            }
        }
        #pragma unroll
        for (int kf = 0; kf < 2; kf++) {
            short8v a0 = *reinterpret_cast<const short8v*>(asB + aoff[0][kf]);
            short8v a1 = *reinterpret_cast<const short8v*>(asB + aoff[1][kf]);
            #pragma unroll
            for (int nf = 0; nf < 4; nf++) {
                short8v bg = *reinterpret_cast<const short8v*>(bgB + boff[nf][kf]);
                short8v bu = *reinterpret_cast<const short8v*>(buB + boff[nf][kf]);
                accg[0][nf] = mfma_bf16(a0, bg, accg[0][nf]);
                accg[1][nf] = mfma_bf16(a1, bg, accg[1][nf]);
                accu[0][nf] = mfma_bf16(a0, bu, accu[0][nf]);
                accu[1][nf] = mfma_bf16(a1, bu, accu[1][nf]);
            }
        }
    }

    // epilogue: silu(g)*u (*score), bf16 store. C/D: col=lane&15, row=(lane>>4)*4+j
    #pragma unroll
    for (int mf = 0; mf < 2; mf++) {
        #pragma unroll
        for (int j = 0; j < 4; j++) {
            int ml = wr * 32 + mf * 16 + lk * 4 + j;
            int m = m0 + ml;
            if (m >= M) continue;
            float sc = 1.f;
            unsigned short* drow;
            if (ez == E_NUM) drow = H1s + (size_t)m * H_DIM;
            else { sc = list_sc[beg + m]; drow = H1r + (size_t)(beg + m) * H_DIM; }
            int cb = h0 + wc * 64 + lrow;
            #pragma unroll
            for (int nf = 0; nf < 4; nf++) {
                float g = accg[mf][nf][j];
                float u = accu[mf][nf][j];
                float h = g / (1.f + expf(-g)) * u * sc;
                drow[cb + nf * 16] = f2bf(h);
            }
        }
    }
}

// ---------------------------------------------------------------------------
// down (MFMA bf16): out = H1 @ Wd_t. routed=0: shared expert, plain stores
// (covers every out element). routed=1: z=expert, atomicAdd (after shared).
// T14 prefetch as in gemm1.
// ---------------------------------------------------------------------------
__global__ __launch_bounds__(256)
void down_kernel(const unsigned short* __restrict__ H1s, const unsigned short* __restrict__ H1r,
                 const unsigned short* __restrict__ Wd_t, const int* __restrict__ counts,
                 const int* __restrict__ list_tok, float* __restrict__ out, int routed) {
    int beg = 0, M, eidx;
    if (routed) {
        int e = blockIdx.z;
        int offs[E_NUM + 1];
        calc_offs(counts, offs);
        beg = offs[e]; M = counts[e]; eidx = e;
    } else { M = N_TOK; eidx = E_NUM; }
    int m0 = blockIdx.x * 64;
    if (m0 >= M) return;
    int n0 = blockIdx.y * 128;

    __shared__ unsigned short As[64 * 64];
    __shared__ unsigned short Bs[128 * 64];
    char* asB = (char*)As;
    char* bsB = (char*)Bs;

    int t = threadIdx.x;
    int arow = t >> 2;
    int as0  = (t & 3) * 2;
    int mrow = m0 + arow;
    int idx  = mrow < M ? mrow : M - 1;
    const unsigned short* ap =
        routed ? H1r + (size_t)(beg + idx) * H_DIM : H1s + (size_t)idx * H_DIM;
    unsigned aw0 = ((unsigned)(arow * 128 + as0 * 16))       ^ ((arow & 7) << 4);
    unsigned aw1 = ((unsigned)(arow * 128 + (as0 + 1) * 16)) ^ ((arow & 7) << 4);

    int brow = t >> 1;
    int bs0  = (t & 1) * 4;
    const unsigned short* bp = Wd_t + (size_t)eidx * 131072 + (size_t)(n0 + brow) * H_DIM;
    unsigned bw[4];
    #pragma unroll
    for (int s = 0; s < 4; s++)
        bw[s] = ((unsigned)(brow * 128 + (bs0 + s) * 16)) ^ ((brow & 7) << 4);

    int wid = t >> 6, lane = t & 63;
    int wr = wid >> 1, wc = wid & 1;
    int lrow = lane & 15, lk = lane >> 4;
    unsigned aoff[2][2], boff[4][2];
    #pragma unroll
    for (int mf = 0; mf < 2; mf++) {
        int r = wr * 32 + mf * 16 + lrow;
        #pragma unroll
        for (int kf = 0; kf < 2; kf++)
            aoff[mf][kf] = ((unsigned)(r * 128 + lk * 16 + kf * 64)) ^ ((r & 7) << 4);
    }
    #pragma unroll
    for (int nf = 0; nf < 4; nf++) {
        int r = wc * 64 + nf * 16 + lrow;
        #pragma unroll
        for (int kf = 0; kf < 2; kf++)
            boff[nf][kf] = ((unsigned)(r * 128 + lk * 16 + kf * 64)) ^ ((r & 7) << 4);
    }

    floatx4 zf = {0.f, 0.f, 0.f, 0.f};
    floatx4 acc[2][4];
    #pragma unroll
    for (int i = 0; i < 2; i++)
        #pragma unroll
        for (int j = 0; j < 4; j++) acc[i][j] = zf;

    // prologue: load k-tile 0
    uint4 av[2], bv[4];
    #pragma unroll
    for (int s = 0; s < 2; s++)
        av[s] = *reinterpret_cast<const uint4*>(ap + (as0 + s) * 8);
    #pragma unroll
    for (int s = 0; s < 4; s++)
        bv[s] = *reinterpret_cast<const uint4*>(bp + (bs0 + s) * 8);

    #pragma unroll
    for (int k0 = 0; k0 < H_DIM; k0 += 64) {
        __syncthreads();
        *reinterpret_cast<uint4*>(asB + aw0) = av[0];
        *reinterpret_cast<uint4*>(asB + aw1) = av[1];
        #pragma unroll
        for (int s = 0; s < 4; s++)
            *reinterpret_cast<uint4*>(bsB + bw[s]) = bv[s];
        __syncthreads();
        if (k0 + 64 < H_DIM) {
            #pragma unroll
            for (int s = 0; s < 2; s++)
                av[s] = *reinterpret_cast<const uint4*>(ap + k0 + 64 + (as0 + s) * 8);
            #pragma unroll
            for (int s = 0; s < 4; s++)
                bv[s] = *reinterpret_cast<const uint4*>(bp + k0 + 64 + (bs0 + s) * 8);
        }
        #pragma unroll
        for (int kf = 0; kf < 2; kf++) {
            short8v a0 = *reinterpret_cast<const short8v*>(asB + aoff[0][kf]);
            short8v a1 = *reinterpret_cast<const short8v*>(asB + aoff[1][kf]);
            #pragma unroll
            for (int nf = 0; nf < 4; nf++) {
                short8v b = *reinterpret_cast<const short8v*>(bsB + boff[nf][kf]);
                acc[0][nf] = mfma_bf16(a0, b, acc[0][nf]);
                acc[1][nf] = mfma_bf16(a1, b, acc[1][nf]);
            }
        }
    }

    #pragma unroll
    for (int mf = 0; mf < 2; mf++) {
        #pragma unroll
        for (int j = 0; j < 4; j++) {
            int ml = wr * 32 + mf * 16 + lk * 4 + j;
            int m = m0 + ml;
            if (m >= M) continue;
            if (!routed) {
                float* orow = out + (size_t)m * D_DIM + n0 + wc * 64 + lrow;
                #pragma unroll
                for (int nf = 0; nf < 4; nf++) orow[nf * 16] = acc[mf][nf][j];
            } else {
                int tok = list_tok[beg + m];
                float* orow = out + (size_t)tok * D_DIM + n0 + wc * 64 + lrow;
                #pragma unroll
                for (int nf = 0; nf < 4; nf++) atomicAdd(&orow[nf * 16], acc[mf][nf][j]);
            }
        }
    }
}

// ---------------------------------------------------------------------------
extern "C" void kernel_launch(void* const* d_in, const int* in_sizes, int n_in,
                              void* d_out, int out_size, void* d_ws, size_t ws_size,
                              hipStream_t stream) {
    const float* x      = (const float*)d_in[0];
    const float* router = (const float*)d_in[1];
    const float* shg    = (const float*)d_in[2];
    const float* shu    = (const float*)d_in[3];
    const float* shd    = (const float*)d_in[4];
    const float* Wg     = (const float*)d_in[5];
    const float* Wu     = (const float*)d_in[6];
    const float* Wd     = (const float*)d_in[7];
    float* out = (float*)d_out;

    // ws layout (~13.5 MB)
    char* ws = (char*)d_ws;
    int*   counts   = (int*)(ws + 0);
    int*   nextp    = (int*)(ws + 64);
    int*   topk_idx = (int*)(ws + 256);
    float* topk_sc  = (float*)(ws + 256 + 1 * 32768);
    int*   list_tok = (int*)(ws + 256 + 2 * 32768);
    float* list_sc  = (float*)(ws + 256 + 3 * 32768);
    unsigned short* Wg_t = (unsigned short*)(ws + 256 + 4 * 32768);  // 9*131072 bf16
    unsigned short* Wu_t = Wg_t + 9 * 131072;
    unsigned short* Wd_t = Wu_t + 9 * 131072;
    unsigned short* H1s  = Wd_t + 9 * 131072;                        // 4096*256 bf16
    unsigned short* H1r  = H1s + (size_t)N_TOK * H_DIM;              // 8192*256 bf16

    hipLaunchKernelGGL(init_kernel,   dim3(1),  dim3(64),  0, stream, counts, nextp);
    hipLaunchKernelGGL(router_kernel, dim3(256), dim3(256), 0, stream,
                       x, router, topk_idx, topk_sc, counts);
    hipLaunchKernelGGL(place_kernel,  dim3(16), dim3(256), 0, stream,
                       topk_idx, topk_sc, counts, nextp, list_tok, list_sc);
    hipLaunchKernelGGL(prep_kernel,   dim3(3456), dim3(256), 0, stream,
                       Wg, Wu, shg, shu, Wd, shd, Wg_t, Wu_t, Wd_t);
    hipLaunchKernelGGL(gemm1_kernel,  dim3(64, 2, 9), dim3(256), 0, stream,
                       x, Wg_t, Wu_t, counts, list_tok, list_sc, H1s, H1r);
    hipLaunchKernelGGL(down_kernel,   dim3(64, 4, 1), dim3(256), 0, stream,
                       H1s, H1r, Wd_t, counts, list_tok, out, 0);
    hipLaunchKernelGGL(down_kernel,   dim3(64, 4, 8), dim3(256), 0, stream,
                       H1s, H1r, Wd_t, counts, list_tok, out, 1);
}

// Round 9
// 187.524 us; speedup vs baseline: 1.2471x; 1.2471x over previous
//
#include <hip/hip_runtime.h>
#include <hip/hip_bf16.h>
#include <math.h>

#define N_TOK 4096
#define D_DIM 512
#define E_NUM 8
#define H_DIM 256

typedef __attribute__((ext_vector_type(8))) short short8v;   // 8 bf16
typedef __attribute__((ext_vector_type(4))) float floatx4;   // MFMA acc

union U4S8 { uint4 u; short8v s; };

__device__ inline floatx4 mfma_bf16(short8v a, short8v b, floatx4 c) {
    return __builtin_amdgcn_mfma_f32_16x16x32_bf16(a, b, c, 0, 0, 0);
}

__device__ inline unsigned short f2bf(float f) {           // RNE fp32->bf16
    union { float f; unsigned u; } v; v.f = f;
    unsigned r = v.u + 0x7FFFu + ((v.u >> 16) & 1u);
    return (unsigned short)(r >> 16);
}
__device__ inline unsigned pack2(float a, float b) {
    return (unsigned)f2bf(a) | ((unsigned)f2bf(b) << 16);
}
__device__ inline void calc_offs(const int* __restrict__ counts, int* offs) {
    int a = 0;
    #pragma unroll
    for (int e = 0; e < E_NUM; e++) { offs[e] = a; a += counts[e]; }
    offs[E_NUM] = a;
}

// ---------------------------------------------------------------------------
__global__ void init_kernel(int* counts, int* nextp) {
    int t = threadIdx.x;
    if (t < 16) { counts[t] = 0; nextp[t] = 0; }
}

// ---------------------------------------------------------------------------
// router v2 (unchanged): wave per 4 tokens, R in regs, exact fp32 top-2
// ---------------------------------------------------------------------------
__global__ __launch_bounds__(256)
void router_kernel(const float* __restrict__ x, const float* __restrict__ router,
                   int* __restrict__ topk_idx, float* __restrict__ topk_sc,
                   int* __restrict__ counts) {
    __shared__ int csh[E_NUM];
    int t = threadIdx.x;
    if (t < E_NUM) csh[t] = 0;
    __syncthreads();

    int wave = t >> 6, lane = t & 63;
    float R[8][8];
    #pragma unroll
    for (int q = 0; q < 8; q++) {
        #pragma unroll
        for (int h = 0; h < 2; h++) {
            float4 v = *reinterpret_cast<const float4*>(
                router + (size_t)(lane * 8 + q) * E_NUM + h * 4);
            R[q][h * 4 + 0] = v.x; R[q][h * 4 + 1] = v.y;
            R[q][h * 4 + 2] = v.z; R[q][h * 4 + 3] = v.w;
        }
    }
    int cnt[E_NUM];
    #pragma unroll
    for (int e = 0; e < E_NUM; e++) cnt[e] = 0;

    #pragma unroll
    for (int it = 0; it < 4; it++) {
        int n = (blockIdx.x * 4 + wave) * 4 + it;
        const float* xr = x + (size_t)n * D_DIM + lane * 8;
        float4 xa = *reinterpret_cast<const float4*>(xr);
        float4 xb = *reinterpret_cast<const float4*>(xr + 4);
        float xs[8] = {xa.x, xa.y, xa.z, xa.w, xb.x, xb.y, xb.z, xb.w};

        float acc[E_NUM];
        #pragma unroll
        for (int e = 0; e < E_NUM; e++) acc[e] = 0.f;
        #pragma unroll
        for (int q = 0; q < 8; q++)
            #pragma unroll
            for (int e = 0; e < E_NUM; e++)
                acc[e] = fmaf(xs[q], R[q][e], acc[e]);
        #pragma unroll
        for (int s = 1; s < 64; s <<= 1) {
            #pragma unroll
            for (int e = 0; e < E_NUM; e++)
                acc[e] += __shfl_xor(acc[e], s);
        }
        float mx = acc[0];
        #pragma unroll
        for (int e = 1; e < E_NUM; e++) mx = fmaxf(mx, acc[e]);
        float p[E_NUM], s = 0.f;
        #pragma unroll
        for (int e = 0; e < E_NUM; e++) { p[e] = expf(acc[e] - mx); s += p[e]; }
        float inv = 1.f / s;

        int i0 = 0; float p0 = p[0];
        #pragma unroll
        for (int e = 1; e < E_NUM; e++)
            if (p[e] > p0) { p0 = p[e]; i0 = e; }
        int i1 = -1; float p1 = -1.f;
        #pragma unroll
        for (int e = 0; e < E_NUM; e++)
            if (e != i0 && p[e] > p1) { p1 = p[e]; i1 = e; }

        if (lane == 0) {
            topk_idx[n * 2 + 0] = i0;
            topk_idx[n * 2 + 1] = i1;
            topk_sc[n * 2 + 0]  = p0 * inv;
            topk_sc[n * 2 + 1]  = p1 * inv;
            #pragma unroll
            for (int e = 0; e < E_NUM; e++)
                cnt[e] += (i0 == e) + (i1 == e);
        }
    }
    if (lane == 0) {
        #pragma unroll
        for (int e = 0; e < E_NUM; e++)
            if (cnt[e]) atomicAdd(&csh[e], cnt[e]);
    }
    __syncthreads();
    if (t < E_NUM && csh[t]) atomicAdd(&counts[t], csh[t]);
}

// ---------------------------------------------------------------------------
// place (unchanged)
// ---------------------------------------------------------------------------
__global__ __launch_bounds__(256)
void place_kernel(const int* __restrict__ topk_idx, const float* __restrict__ topk_sc,
                  const int* __restrict__ counts, int* __restrict__ nextp,
                  int* __restrict__ list_tok, float* __restrict__ list_sc) {
    int offs[E_NUM + 1];
    calc_offs(counts, offs);
    int n = blockIdx.x * 256 + threadIdx.x;
    int lane = threadIdx.x & 63;
    for (int k = 0; k < 2; k++) {
        int e = topk_idx[n * 2 + k];
        float sc = topk_sc[n * 2 + k];
        #pragma unroll
        for (int ee = 0; ee < E_NUM; ee++) {
            unsigned long long m = __ballot(e == ee);
            if (m == 0ull) continue;
            int leader = __ffsll((long long)m) - 1;
            int base = 0;
            if (lane == leader) base = atomicAdd(&nextp[ee], (int)__popcll(m));
            base = __shfl(base, leader);
            if (e == ee) {
                int pos = base + (int)__popcll(m & ((1ull << lane) - 1ull));
                int slot = offs[ee] + pos;
                list_tok[slot] = n;
                list_sc[slot]  = sc;
            }
        }
    }
}

// ---------------------------------------------------------------------------
// prep_frag: repack weights into MFMA-native fragment streams (bf16).
// WguF panels: [(e*2+gu)*16+nt][ks=0..15][lane] 16B; frag[l] =
//   W[k=ks*32+(l>>4)*8+j][n=nt*16+(l&15)], j=0..7.  (288 panels, 4.5 MB)
// WdF panels:  [e*32+nt][ks=0..7][lane] 16B, same formula.  (288 panels)
// One wave per panel; 576 jobs over 144 blocks.
// ---------------------------------------------------------------------------
__global__ __launch_bounds__(256)
void prep_frag(const float* __restrict__ Wg, const float* __restrict__ Wu,
               const float* __restrict__ shg, const float* __restrict__ shu,
               const float* __restrict__ Wd, const float* __restrict__ shd,
               unsigned short* __restrict__ WguF, unsigned short* __restrict__ WdF) {
    int wid = threadIdx.x >> 6, lane = threadIdx.x & 63;
    int job = blockIdx.x * 4 + wid;
    int kg = lane >> 4, ln = lane & 15;
    if (job < 288) {                                   // gate/up family
        int e = job >> 5, r = job & 31, gu = r >> 4, nt = r & 15;
        const float* S = (e < E_NUM) ? ((gu ? Wu : Wg) + (size_t)e * 131072)
                                     : (gu ? shu : shg);
        unsigned short* D = WguF + ((size_t)((e * 2 + gu) * 16 + nt) * 16) * 512 + lane * 8;
        for (int ks = 0; ks < 16; ks++) {
            float v[8];
            #pragma unroll
            for (int j = 0; j < 8; j++)
                v[j] = S[(size_t)(ks * 32 + kg * 8 + j) * H_DIM + nt * 16 + ln];
            uint4 o;
            o.x = pack2(v[0], v[1]); o.y = pack2(v[2], v[3]);
            o.z = pack2(v[4], v[5]); o.w = pack2(v[6], v[7]);
            *reinterpret_cast<uint4*>(D + ks * 512) = o;
        }
    } else if (job < 576) {                            // down family
        int j2 = job - 288;
        int e = j2 >> 5, nt = j2 & 31;
        const float* S = (e < E_NUM) ? (Wd + (size_t)e * 131072) : shd;
        unsigned short* D = WdF + ((size_t)(e * 32 + nt) * 8) * 512 + lane * 8;
        for (int ks = 0; ks < 8; ks++) {
            float v[8];
            #pragma unroll
            for (int j = 0; j < 8; j++)
                v[j] = S[(size_t)(ks * 32 + kg * 8 + j) * D_DIM + nt * 16 + ln];
            uint4 o;
            o.x = pack2(v[0], v[1]); o.y = pack2(v[2], v[3]);
            o.z = pack2(v[4], v[5]); o.w = pack2(v[6], v[7]);
            *reinterpret_cast<uint4*>(D + ks * 512) = o;
        }
    }
}

// ---------------------------------------------------------------------------
// gemm1 v3: barrier-free, LDS-free. Wave = 16 rows x 64 cols.
// A: direct gather reads of x (fp32->bf16 in reg); B: fragment streams.
// grid (64, 4, 9): stile = bx*4+wid, col panel nt0 = by*4, z = expert (8=shared)
// ---------------------------------------------------------------------------
__global__ __launch_bounds__(256)
void gemm1_kernel(const float* __restrict__ x, const unsigned short* __restrict__ WguF,
                  const int* __restrict__ counts, const int* __restrict__ list_tok,
                  const float* __restrict__ list_sc,
                  unsigned short* __restrict__ H1s, unsigned short* __restrict__ H1r) {
    int ez = blockIdx.z;
    int offs[E_NUM + 1];
    calc_offs(counts, offs);
    int beg = 0, M;
    if (ez == E_NUM) { M = N_TOK; }
    else { beg = offs[ez]; M = counts[ez]; }
    int wid = threadIdx.x >> 6, lane = threadIdx.x & 63;
    int stile = blockIdx.x * 4 + wid;
    if (stile * 16 >= M) return;
    int nt0 = blockIdx.y * 4;
    int kg = lane >> 4, ln = lane & 15;

    int m_lane = stile * 16 + ln;
    int srow;
    if (ez == E_NUM) srow = m_lane;
    else srow = list_tok[beg + (m_lane < M ? m_lane : M - 1)];
    const float* ap = x + (size_t)srow * D_DIM + kg * 8;

    const unsigned short* bgp = WguF + ((size_t)((ez * 2 + 0) * 16 + nt0) * 16) * 512 + lane * 8;
    const unsigned short* bup = WguF + ((size_t)((ez * 2 + 1) * 16 + nt0) * 16) * 512 + lane * 8;

    floatx4 zf = {0.f, 0.f, 0.f, 0.f};
    floatx4 accg[4], accu[4];
    #pragma unroll
    for (int nf = 0; nf < 4; nf++) { accg[nf] = zf; accu[nf] = zf; }

    float4 aL[2], aH[2];
    uint4 vg[2][4], vu[2][4];
    aL[0] = *reinterpret_cast<const float4*>(ap);
    aH[0] = *reinterpret_cast<const float4*>(ap + 4);
    #pragma unroll
    for (int nf = 0; nf < 4; nf++) {
        vg[0][nf] = *reinterpret_cast<const uint4*>(bgp + nf * 8192);
        vu[0][nf] = *reinterpret_cast<const uint4*>(bup + nf * 8192);
    }
    #pragma unroll
    for (int ks = 0; ks < 16; ks++) {
        const int cur = ks & 1, nxt = cur ^ 1;
        if (ks < 15) {
            aL[nxt] = *reinterpret_cast<const float4*>(ap + (ks + 1) * 32);
            aH[nxt] = *reinterpret_cast<const float4*>(ap + (ks + 1) * 32 + 4);
            #pragma unroll
            for (int nf = 0; nf < 4; nf++) {
                vg[nxt][nf] = *reinterpret_cast<const uint4*>(bgp + nf * 8192 + (ks + 1) * 512);
                vu[nxt][nf] = *reinterpret_cast<const uint4*>(bup + nf * 8192 + (ks + 1) * 512);
            }
        }
        U4S8 A;
        A.u.x = pack2(aL[cur].x, aL[cur].y);
        A.u.y = pack2(aL[cur].z, aL[cur].w);
        A.u.z = pack2(aH[cur].x, aH[cur].y);
        A.u.w = pack2(aH[cur].z, aH[cur].w);
        #pragma unroll
        for (int nf = 0; nf < 4; nf++) {
            U4S8 g, u; g.u = vg[cur][nf]; u.u = vu[cur][nf];
            accg[nf] = mfma_bf16(A.s, g.s, accg[nf]);
            accu[nf] = mfma_bf16(A.s, u.s, accu[nf]);
        }
    }

    // epilogue: C/D row=(l>>4)*4+j, col=l&15. silu(g)*u (*score), bf16 store.
    #pragma unroll
    for (int j = 0; j < 4; j++) {
        int m = stile * 16 + kg * 4 + j;
        if (m >= M) continue;
        float sc = 1.f;
        unsigned short* drow;
        if (ez == E_NUM) drow = H1s + (size_t)m * H_DIM;
        else { sc = list_sc[beg + m]; drow = H1r + (size_t)(beg + m) * H_DIM; }
        #pragma unroll
        for (int nf = 0; nf < 4; nf++) {
            float g = accg[nf][j];
            float u = accu[nf][j];
            float h = g / (1.f + expf(-g)) * u * sc;
            drow[(nt0 + nf) * 16 + ln] = f2bf(h);
        }
    }
}

// ---------------------------------------------------------------------------
// down v3: barrier-free, LDS-free. Wave = 16 rows x 64 cols, K=256 (8 ksteps).
// routed=0: shared expert, plain stores cover all of out (runs first).
// routed=1: per-expert atomicAdd.
// ---------------------------------------------------------------------------
__global__ __launch_bounds__(256)
void down_kernel(const unsigned short* __restrict__ H1s, const unsigned short* __restrict__ H1r,
                 const unsigned short* __restrict__ WdF, const int* __restrict__ counts,
                 const int* __restrict__ list_tok, float* __restrict__ out, int routed) {
    int beg = 0, M, eidx;
    if (routed) {
        int e = blockIdx.z;
        int offs[E_NUM + 1];
        calc_offs(counts, offs);
        beg = offs[e]; M = counts[e]; eidx = e;
    } else { M = N_TOK; eidx = E_NUM; }
    int wid = threadIdx.x >> 6, lane = threadIdx.x & 63;
    int stile = blockIdx.x * 4 + wid;
    if (stile * 16 >= M) return;
    int nt0 = blockIdx.y * 4;
    int kg = lane >> 4, ln = lane & 15;

    const unsigned short* H1 = routed ? H1r : H1s;
    const unsigned short* ap = H1 + (size_t)(beg + stile * 16 + ln) * H_DIM + kg * 8;
    const unsigned short* bp = WdF + ((size_t)(eidx * 32 + nt0) * 8) * 512 + lane * 8;

    floatx4 zf = {0.f, 0.f, 0.f, 0.f};
    floatx4 acc[4];
    #pragma unroll
    for (int nf = 0; nf < 4; nf++) acc[nf] = zf;

    uint4 av[2], bv[2][4];
    av[0] = *reinterpret_cast<const uint4*>(ap);
    #pragma unroll
    for (int nf = 0; nf < 4; nf++)
        bv[0][nf] = *reinterpret_cast<const uint4*>(bp + nf * 4096);
    #pragma unroll
    for (int ks = 0; ks < 8; ks++) {
        const int cur = ks & 1, nxt = cur ^ 1;
        if (ks < 7) {
            av[nxt] = *reinterpret_cast<const uint4*>(ap + (ks + 1) * 32);
            #pragma unroll
            for (int nf = 0; nf < 4; nf++)
                bv[nxt][nf] = *reinterpret_cast<const uint4*>(bp + nf * 4096 + (ks + 1) * 512);
        }
        U4S8 A; A.u = av[cur];
        #pragma unroll
        for (int nf = 0; nf < 4; nf++) {
            U4S8 b; b.u = bv[cur][nf];
            acc[nf] = mfma_bf16(A.s, b.s, acc[nf]);
        }
    }

    #pragma unroll
    for (int j = 0; j < 4; j++) {
        int m = stile * 16 + kg * 4 + j;
        if (m >= M) continue;
        if (!routed) {
            float* orow = out + (size_t)m * D_DIM;
            #pragma unroll
            for (int nf = 0; nf < 4; nf++)
                orow[(nt0 + nf) * 16 + ln] = acc[nf][j];
        } else {
            int tok = list_tok[beg + m];
            float* orow = out + (size_t)tok * D_DIM;
            #pragma unroll
            for (int nf = 0; nf < 4; nf++)
                atomicAdd(&orow[(nt0 + nf) * 16 + ln], acc[nf][j]);
        }
    }
}

// ---------------------------------------------------------------------------
extern "C" void kernel_launch(void* const* d_in, const int* in_sizes, int n_in,
                              void* d_out, int out_size, void* d_ws, size_t ws_size,
                              hipStream_t stream) {
    const float* x      = (const float*)d_in[0];
    const float* router = (const float*)d_in[1];
    const float* shg    = (const float*)d_in[2];
    const float* shu    = (const float*)d_in[3];
    const float* shd    = (const float*)d_in[4];
    const float* Wg     = (const float*)d_in[5];
    const float* Wu     = (const float*)d_in[6];
    const float* Wd     = (const float*)d_in[7];
    float* out = (float*)d_out;

    // ws layout (~12.9 MB)
    char* ws = (char*)d_ws;
    int*   counts   = (int*)(ws + 0);
    int*   nextp    = (int*)(ws + 64);
    int*   topk_idx = (int*)(ws + 256);
    float* topk_sc  = (float*)(ws + 256 + 1 * 32768);
    int*   list_tok = (int*)(ws + 256 + 2 * 32768);
    float* list_sc  = (float*)(ws + 256 + 3 * 32768);
    unsigned short* WguF = (unsigned short*)(ws + 256 + 4 * 32768);  // 288*16*512 u16 = 4.5MB
    unsigned short* WdF  = WguF + (size_t)288 * 16 * 512;            // 288*8*512 u16 = 2.25MB
    unsigned short* H1s  = WdF + (size_t)288 * 8 * 512;              // 4096*256 bf16
    unsigned short* H1r  = H1s + (size_t)N_TOK * H_DIM;              // (8192+64)*256 bf16

    hipLaunchKernelGGL(init_kernel,   dim3(1),   dim3(64),  0, stream, counts, nextp);
    hipLaunchKernelGGL(router_kernel, dim3(256), dim3(256), 0, stream,
                       x, router, topk_idx, topk_sc, counts);
    hipLaunchKernelGGL(place_kernel,  dim3(16),  dim3(256), 0, stream,
                       topk_idx, topk_sc, counts, nextp, list_tok, list_sc);
    hipLaunchKernelGGL(prep_frag,     dim3(144), dim3(256), 0, stream,
                       Wg, Wu, shg, shu, Wd, shd, WguF, WdF);
    hipLaunchKernelGGL(gemm1_kernel,  dim3(64, 4, 9), dim3(256), 0, stream,
                       x, WguF, counts, list_tok, list_sc, H1s, H1r);
    hipLaunchKernelGGL(down_kernel,   dim3(64, 8, 1), dim3(256), 0, stream,
                       H1s, H1r, WdF, counts, list_tok, out, 0);
    hipLaunchKernelGGL(down_kernel,   dim3(64, 8, 8), dim3(256), 0, stream,
                       H1s, H1r, WdF, counts, list_tok, out, 1);
}